// Round 1
// baseline (167.563 us; speedup 1.0000x reference)
//
#include <hip/hip_runtime.h>
#include <stdint.h>

#define COLUMNS   1024
#define CELLS     16
#define NUM_CELLS (COLUMNS * CELLS)   // 16384
#define SEGS      32
#define SYNS      128
#define ACT_THR   10

// ---------------------------------------------------------------------------
// Kernel 0: pack prev_active_cells (bool array, dtype auto-detected) into a
// 512-word bitmask in workspace. One block of 512 threads.
// ---------------------------------------------------------------------------
__global__ __launch_bounds__(512) void pack_prev_kernel(
    const void* __restrict__ prev, uint32_t* __restrict__ prevbits)
{
    __shared__ int s_isu8;
    const int* pi = (const int*)prev;
    if (threadIdx.x == 0) s_isu8 = 0;
    __syncthreads();
    // If stored as int32 bools, every 32-bit word is 0 or 1. If stored as
    // uint8 bools (random 0/1 bytes), some packed word exceeds 1 w.h.p.
    int bad = 0;
    for (int k = threadIdx.x; k < NUM_CELLS / 4; k += 512)
        if ((unsigned)pi[k] > 1u) bad = 1;
    if (bad) atomicOr(&s_isu8, 1);
    __syncthreads();

    int w = threadIdx.x;  // 512 words, 32 cells each
    uint32_t m = 0;
    if (s_isu8) {
        const unsigned char* p = (const unsigned char*)prev + (size_t)w * 32;
        #pragma unroll
        for (int j = 0; j < 32; ++j) m |= (p[j] ? 1u : 0u) << j;
    } else {
        const int* p = pi + (size_t)w * 32;
        #pragma unroll
        for (int j = 0; j < 32; ++j) m |= (p[j] ? 1u : 0u) << j;
    }
    prevbits[w] = m;
}

// ---------------------------------------------------------------------------
// Kernel 1 (phases 1+2 fused scan): one block per cell. Skips inactive
// columns entirely (their pred1/bestseg are never consumed). Computes:
//   pred1[cell]   = any segment with >=ACT_THR (connected & prev_active) syn
//   bestseg[cell] = first-argmax over segments of sum(prev_active[conn])
// ---------------------------------------------------------------------------
__global__ __launch_bounds__(256) void phase1_kernel(
    const int* __restrict__ x, const uint32_t* __restrict__ prevbits,
    const int* __restrict__ conn, const float* __restrict__ vol,
    const float* __restrict__ cons,
    unsigned char* __restrict__ pred1, unsigned char* __restrict__ bestseg)
{
    const int cell = blockIdx.x;
    const int col  = cell >> 4;
    if (x[col] == 0) return;

    __shared__ uint32_t sbits[NUM_CELLS / 32];
    __shared__ int sovl[SEGS];
    __shared__ int sfire;
    for (int i = threadIdx.x; i < NUM_CELLS / 32; i += 256) sbits[i] = prevbits[i];
    if (threadIdx.x == 0) sfire = 0;
    __syncthreads();

    const int wave = threadIdx.x >> 6;
    const int lane = threadIdx.x & 63;
    const size_t base = (size_t)cell * (SEGS * SYNS);

    int fire = 0;
    #pragma unroll
    for (int k = 0; k < 8; ++k) {
        const int s = wave * 8 + k;
        const size_t off = base + (size_t)s * SYNS + lane * 2;
        int2   c = *(const int2*)(conn + off);
        float2 v = *(const float2*)(vol + off);
        float2 q = *(const float2*)(cons + off);
        int i0 = min(max(c.x, 0), NUM_CELLS - 1);
        int i1 = min(max(c.y, 0), NUM_CELLS - 1);
        int p0 = (sbits[i0 >> 5] >> (i0 & 31)) & 1;
        int p1 = (sbits[i1 >> 5] >> (i1 & 31)) & 1;
        int c0 = (v.x > 0.5f) || (q.x > 0.5f);
        int c1 = (v.y > 0.5f) || (q.y > 0.5f);
        unsigned long long bc0 = __ballot(c0 && p0);
        unsigned long long bc1 = __ballot(c1 && p1);
        unsigned long long bp0 = __ballot(p0 != 0);
        unsigned long long bp1 = __ballot(p1 != 0);
        if (lane == 0) {
            int cnt = __popcll(bc0) + __popcll(bc1);
            sovl[s] = __popcll(bp0) + __popcll(bp1);
            if (cnt >= ACT_THR) fire = 1;
        }
    }
    if (lane == 0 && fire) atomicOr(&sfire, 1);
    __syncthreads();

    if (threadIdx.x == 0) {
        int best = -1, bi = 0;
        #pragma unroll
        for (int s = 0; s < SEGS; ++s)
            if (sovl[s] > best) { best = sovl[s]; bi = s; }  // first max (jnp.argmax)
        pred1[cell]   = (unsigned char)sfire;
        bestseg[cell] = (unsigned char)bi;
    }
}

// ---------------------------------------------------------------------------
// Kernel 2 (mid, one block of 1024 = one thread per column):
//   col_has_pred, new_active (floats to d_out[0..N) + packed bits to ws),
//   n_act/n_pred -> acc (d_out[2N]), learn_on flag.
// ---------------------------------------------------------------------------
__global__ __launch_bounds__(1024) void mid_kernel(
    const int* __restrict__ x, const float* __restrict__ mod,
    const uint32_t* __restrict__ prevbits, const unsigned char* __restrict__ pred1,
    uint32_t* __restrict__ newbits, int* __restrict__ learnflag,
    float* __restrict__ out)
{
    __shared__ unsigned char s_hp[COLUMNS];
    __shared__ unsigned char s_act[COLUMNS];
    __shared__ int s_nact, s_npred, s_anyprev;
    const int t = threadIdx.x;
    if (t == 0) { s_nact = 0; s_npred = 0; s_anyprev = 0; }
    __syncthreads();

    {   // one column per thread
        const int col = t;
        int ca = (x[col] != 0) ? 1 : 0;
        int hp = 0;
        if (ca) {
            #pragma unroll
            for (int k = 0; k < CELLS; ++k) hp |= pred1[col * CELLS + k];
            hp = hp ? 1 : 0;
        }
        s_act[col] = (unsigned char)ca;
        s_hp[col]  = (unsigned char)hp;
        unsigned long long ba = __ballot(ca != 0);
        unsigned long long bp = __ballot((ca && hp) != 0);
        if ((t & 63) == 0) {
            atomicAdd(&s_nact, __popcll(ba));
            atomicAdd(&s_npred, __popcll(bp));
        }
    }
    if (t < NUM_CELLS / 32) {
        unsigned long long b = __ballot(prevbits[t] != 0);
        if ((t & 63) == 0 && b) atomicOr(&s_anyprev, 1);
    }
    __syncthreads();

    // new_active: packed bits (512 words) + float outputs
    if (t < NUM_CELLS / 32) {
        uint32_t m = 0;
        #pragma unroll
        for (int j = 0; j < 32; ++j) {
            const int cell = t * 32 + j;
            const int col  = cell >> 4;
            int na = s_act[col] && (s_hp[col] ? (pred1[cell] != 0) : 1);
            m |= (uint32_t)(na ? 1u : 0u) << j;
        }
        newbits[t] = m;
    }
    for (int i = t; i < NUM_CELLS; i += 1024) {
        const int col = i >> 4;
        int na = s_act[col] && (s_hp[col] ? (pred1[i] != 0) : 1);
        out[i] = na ? 1.0f : 0.0f;
    }
    __syncthreads();

    if (t == 0) {
        float acc = (s_nact > 0)
                  ? (float)s_npred / (float)max(s_nact, 1)
                  : 1.0f;
        out[2 * NUM_CELLS] = acc;
        *learnflag = ((mod[0] != 0.0f) && (s_anyprev != 0)) ? 1 : 0;
    }
}

// ---------------------------------------------------------------------------
// Kernel 3 (phase 3 scan): one block per cell. Inactive columns just write 0.
// vol2 is never materialized: on the (single) updated segment of a winner
// cell, apply delta inline; clip(x,0,1)>0.5 == x>0.5 so the comparison is
// exact without clipping.
// ---------------------------------------------------------------------------
__global__ __launch_bounds__(256) void phase3_kernel(
    const int* __restrict__ x, const float* __restrict__ mod,
    const uint32_t* __restrict__ prevbits, const uint32_t* __restrict__ newbits,
    const int* __restrict__ learnflag,
    const int* __restrict__ conn, const float* __restrict__ vol,
    const float* __restrict__ cons, const unsigned char* __restrict__ bestseg,
    float* __restrict__ outpred)
{
    const int cell = blockIdx.x;
    const int col  = cell >> 4;
    if (x[col] == 0) {
        if (threadIdx.x == 0) outpred[cell] = 0.0f;
        return;
    }

    __shared__ uint32_t snew[NUM_CELLS / 32];
    __shared__ uint32_t sprev[NUM_CELLS / 32];
    __shared__ int sfire;
    for (int i = threadIdx.x; i < NUM_CELLS / 32; i += 256) {
        snew[i]  = newbits[i];
        sprev[i] = prevbits[i];
    }
    if (threadIdx.x == 0) sfire = 0;
    __syncthreads();

    const int na = (snew[cell >> 5] >> (cell & 31)) & 1;
    const int upd_seg = (*learnflag && na) ? (int)bestseg[cell] : -1;
    const float d = mod[0] * 0.1f;

    const int wave = threadIdx.x >> 6;
    const int lane = threadIdx.x & 63;
    const size_t base = (size_t)cell * (SEGS * SYNS);

    int fire = 0;
    #pragma unroll
    for (int k = 0; k < 8; ++k) {
        const int s = wave * 8 + k;
        const size_t off = base + (size_t)s * SYNS + lane * 2;
        int2   c = *(const int2*)(conn + off);
        float2 v = *(const float2*)(vol + off);
        float2 q = *(const float2*)(cons + off);
        int i0 = min(max(c.x, 0), NUM_CELLS - 1);
        int i1 = min(max(c.y, 0), NUM_CELLS - 1);
        float vx = v.x, vy = v.y;
        if (s == upd_seg) {
            int pp0 = (sprev[i0 >> 5] >> (i0 & 31)) & 1;
            int pp1 = (sprev[i1 >> 5] >> (i1 & 31)) & 1;
            vx += pp0 ? d : -d;
            vy += pp1 ? d : -d;
        }
        int pn0 = (snew[i0 >> 5] >> (i0 & 31)) & 1;
        int pn1 = (snew[i1 >> 5] >> (i1 & 31)) & 1;
        int c0 = (vx > 0.5f) || (q.x > 0.5f);
        int c1 = (vy > 0.5f) || (q.y > 0.5f);
        unsigned long long b0 = __ballot(c0 && pn0);
        unsigned long long b1 = __ballot(c1 && pn1);
        if (lane == 0) {
            if (__popcll(b0) + __popcll(b1) >= ACT_THR) fire = 1;
        }
    }
    if (lane == 0 && fire) atomicOr(&sfire, 1);
    __syncthreads();
    if (threadIdx.x == 0) outpred[cell] = sfire ? 1.0f : 0.0f;
}

// ---------------------------------------------------------------------------
extern "C" void kernel_launch(void* const* d_in, const int* in_sizes, int n_in,
                              void* d_out, int out_size, void* d_ws, size_t ws_size,
                              hipStream_t stream) {
    const int*   x    = (const int*)d_in[0];
    const float* mod  = (const float*)d_in[1];
    const void*  prev = d_in[2];                 // bool array (dtype auto-detected)
    const int*   conn = (const int*)d_in[3];
    const float* vol  = (const float*)d_in[4];
    const float* cons = (const float*)d_in[5];
    float* out = (float*)d_out;  // [0..N) new_active, [N..2N) new_predictive, [2N] acc

    uint32_t* prevbits  = (uint32_t*)d_ws;               // 512 words
    uint32_t* newbits   = prevbits + 512;                // 512 words
    int*      learnflag = (int*)(newbits + 512);         // 1 word (+pad)
    unsigned char* pred1   = (unsigned char*)(learnflag + 4);
    unsigned char* bestseg = pred1 + NUM_CELLS;

    pack_prev_kernel<<<1, 512, 0, stream>>>(prev, prevbits);
    phase1_kernel<<<NUM_CELLS, 256, 0, stream>>>(x, prevbits, conn, vol, cons,
                                                 pred1, bestseg);
    mid_kernel<<<1, 1024, 0, stream>>>(x, mod, prevbits, pred1, newbits,
                                       learnflag, out);
    phase3_kernel<<<NUM_CELLS, 256, 0, stream>>>(x, mod, prevbits, newbits,
                                                 learnflag, conn, vol, cons,
                                                 bestseg, out + NUM_CELLS);
}

// Round 2
// 140.705 us; speedup vs baseline: 1.1909x; 1.1909x over previous
//
#include <hip/hip_runtime.h>
#include <stdint.h>

#define COLUMNS   1024
#define CELLS     16
#define NUM_CELLS (COLUMNS * CELLS)   // 16384
#define SEGS      32
#define SYNS      128
#define ACT_THR   10

// Reduce v across each 32-lane half of a 64-lane wave (xor masks < 32 never
// cross the half boundary). All lanes in a half end with the half's sum.
__device__ __forceinline__ int reduce_half32(int v) {
    v += __shfl_xor(v, 1);
    v += __shfl_xor(v, 2);
    v += __shfl_xor(v, 4);
    v += __shfl_xor(v, 8);
    v += __shfl_xor(v, 16);
    return v;
}

// ---------------------------------------------------------------------------
// Kernel 0: pack prev_active_cells (bool, dtype auto-detected) into a
// 512-word bitmask. One block of 512 threads.
// ---------------------------------------------------------------------------
__global__ __launch_bounds__(512) void pack_prev_kernel(
    const void* __restrict__ prev, uint32_t* __restrict__ prevbits)
{
    __shared__ int s_isu8;
    const int* pi = (const int*)prev;
    if (threadIdx.x == 0) s_isu8 = 0;
    __syncthreads();
    // int32-bool data: every word is 0/1. uint8-bool data: some word >1 w.h.p.
    int bad = 0;
    for (int k = threadIdx.x; k < NUM_CELLS / 4; k += 512)
        if ((unsigned)pi[k] > 1u) bad = 1;
    if (bad) atomicOr(&s_isu8, 1);
    __syncthreads();

    int w = threadIdx.x;  // 512 words, 32 cells each
    uint32_t m = 0;
    if (s_isu8) {
        const unsigned char* p = (const unsigned char*)prev + (size_t)w * 32;
        #pragma unroll
        for (int j = 0; j < 32; ++j) m |= (p[j] ? 1u : 0u) << j;
    } else {
        const int* p = pi + (size_t)w * 32;
        #pragma unroll
        for (int j = 0; j < 32; ++j) m |= (p[j] ? 1u : 0u) << j;
    }
    prevbits[w] = m;
}

// ---------------------------------------------------------------------------
// Kernel 1 (phases 1+2 fused): one block (256 thr = 4 waves) per cell; skips
// inactive columns. Each wave owns 8 segments; per iteration a wave covers 2
// segments (32 lanes each, int4 = 4 syns/lane). Computes pred1 + bestseg and
// (PACK) writes uint16 sideband {conn_clipped | connected<<14} for phase 3.
// ---------------------------------------------------------------------------
template<bool PACK>
__global__ __launch_bounds__(256) void phase1_kernel(
    const int* __restrict__ x, const uint32_t* __restrict__ prevbits,
    const int* __restrict__ conn, const float* __restrict__ vol,
    const float* __restrict__ cons, unsigned short* __restrict__ packed,
    unsigned char* __restrict__ pred1, unsigned char* __restrict__ bestseg)
{
    const int cell = blockIdx.x;
    const int col  = cell >> 4;
    if (x[col] == 0) return;

    __shared__ uint32_t sbits[NUM_CELLS / 32];
    __shared__ int sovl[SEGS];
    __shared__ int sfire;
    for (int i = threadIdx.x; i < NUM_CELLS / 32; i += 256) sbits[i] = prevbits[i];
    if (threadIdx.x == 0) sfire = 0;
    __syncthreads();

    const int wv   = threadIdx.x >> 6;
    const int ln   = threadIdx.x & 63;
    const int half = ln >> 5;
    const int l32  = ln & 31;
    const size_t base = (size_t)cell * (SEGS * SYNS);

    int fire = 0;
    #pragma unroll
    for (int k = 0; k < 4; ++k) {
        const int seg = wv * 8 + k * 2 + half;
        const size_t off = base + (size_t)seg * SYNS + l32 * 4;
        int4   c = *(const int4*)(conn + off);
        float4 v = *(const float4*)(vol + off);
        float4 q = *(const float4*)(cons + off);
        int i0 = min(max(c.x, 0), NUM_CELLS - 1);
        int i1 = min(max(c.y, 0), NUM_CELLS - 1);
        int i2 = min(max(c.z, 0), NUM_CELLS - 1);
        int i3 = min(max(c.w, 0), NUM_CELLS - 1);
        int p0 = (sbits[i0 >> 5] >> (i0 & 31)) & 1;
        int p1 = (sbits[i1 >> 5] >> (i1 & 31)) & 1;
        int p2 = (sbits[i2 >> 5] >> (i2 & 31)) & 1;
        int p3 = (sbits[i3 >> 5] >> (i3 & 31)) & 1;
        int cn0 = ((v.x > 0.5f) || (q.x > 0.5f)) ? 1 : 0;
        int cn1 = ((v.y > 0.5f) || (q.y > 0.5f)) ? 1 : 0;
        int cn2 = ((v.z > 0.5f) || (q.z > 0.5f)) ? 1 : 0;
        int cn3 = ((v.w > 0.5f) || (q.w > 0.5f)) ? 1 : 0;
        if (PACK) {
            ushort4 pk;
            pk.x = (unsigned short)(i0 | (cn0 << 14));
            pk.y = (unsigned short)(i1 | (cn1 << 14));
            pk.z = (unsigned short)(i2 | (cn2 << 14));
            pk.w = (unsigned short)(i3 | (cn3 << 14));
            *(ushort4*)(packed + off) = pk;
        }
        int cnt = (cn0 & p0) + (cn1 & p1) + (cn2 & p2) + (cn3 & p3);
        int ovl = p0 + p1 + p2 + p3;
        int r = reduce_half32(cnt | (ovl << 8));   // cnt<=128 fits low byte
        if (l32 == 0) {
            sovl[seg] = r >> 8;
            if ((r & 0xFF) >= ACT_THR) fire = 1;
        }
    }
    if (fire) atomicOr(&sfire, 1);
    __syncthreads();

    if (threadIdx.x == 0) {
        int best = -1, bi = 0;
        #pragma unroll
        for (int s = 0; s < SEGS; ++s)
            if (sovl[s] > best) { best = sovl[s]; bi = s; }  // first max (jnp.argmax)
        pred1[cell]   = (unsigned char)sfire;
        bestseg[cell] = (unsigned char)bi;
    }
}

// ---------------------------------------------------------------------------
// Kernel 2 (mid, one block of 1024 = one thread per column):
//   col_has_pred, new_active (floats to d_out[0..N) + packed bits), acc,
//   learn_on flag.
// ---------------------------------------------------------------------------
__global__ __launch_bounds__(1024) void mid_kernel(
    const int* __restrict__ x, const float* __restrict__ mod,
    const uint32_t* __restrict__ prevbits, const unsigned char* __restrict__ pred1,
    uint32_t* __restrict__ newbits, int* __restrict__ learnflag,
    float* __restrict__ out)
{
    __shared__ unsigned char s_hp[COLUMNS];
    __shared__ unsigned char s_act[COLUMNS];
    __shared__ int s_nact, s_npred, s_anyprev;
    const int t = threadIdx.x;
    if (t == 0) { s_nact = 0; s_npred = 0; s_anyprev = 0; }
    __syncthreads();

    {   // one column per thread
        const int col = t;
        int ca = (x[col] != 0) ? 1 : 0;
        int hp = 0;
        if (ca) {
            #pragma unroll
            for (int k = 0; k < CELLS; ++k) hp |= pred1[col * CELLS + k];
            hp = hp ? 1 : 0;
        }
        s_act[col] = (unsigned char)ca;
        s_hp[col]  = (unsigned char)hp;
        unsigned long long ba = __ballot(ca != 0);
        unsigned long long bp = __ballot((ca && hp) != 0);
        if ((t & 63) == 0) {
            atomicAdd(&s_nact, __popcll(ba));
            atomicAdd(&s_npred, __popcll(bp));
        }
    }
    if (t < NUM_CELLS / 32) {
        unsigned long long b = __ballot(prevbits[t] != 0);
        if ((t & 63) == 0 && b) atomicOr(&s_anyprev, 1);
    }
    __syncthreads();

    if (t < NUM_CELLS / 32) {
        uint32_t m = 0;
        #pragma unroll
        for (int j = 0; j < 32; ++j) {
            const int cell = t * 32 + j;
            const int col  = cell >> 4;
            int na = s_act[col] && (s_hp[col] ? (pred1[cell] != 0) : 1);
            m |= (uint32_t)(na ? 1u : 0u) << j;
        }
        newbits[t] = m;
    }
    for (int i = t; i < NUM_CELLS; i += 1024) {
        const int col = i >> 4;
        int na = s_act[col] && (s_hp[col] ? (pred1[i] != 0) : 1);
        out[i] = na ? 1.0f : 0.0f;
    }
    __syncthreads();

    if (t == 0) {
        float acc = (s_nact > 0) ? (float)s_npred / (float)max(s_nact, 1) : 1.0f;
        out[2 * NUM_CELLS] = acc;
        *learnflag = ((mod[0] != 0.0f) && (s_anyprev != 0)) ? 1 : 0;
    }
}

// ---------------------------------------------------------------------------
// Kernel 3 (phase 3): PACKED path streams the uint16 sideband (2 B/syn
// instead of 12 B/syn); only the single updated segment of a winner cell
// re-reads its vol/cons row to recompute `connected` after the learning
// delta (clip(x,0,1)>0.5 == x>0.5, exact). Fallback re-reads everything.
// ---------------------------------------------------------------------------
template<bool PACKED>
__global__ __launch_bounds__(256) void phase3_kernel(
    const int* __restrict__ x, const float* __restrict__ mod,
    const uint32_t* __restrict__ prevbits, const uint32_t* __restrict__ newbits,
    const int* __restrict__ learnflag, const unsigned short* __restrict__ packed,
    const int* __restrict__ conn, const float* __restrict__ vol,
    const float* __restrict__ cons, const unsigned char* __restrict__ bestseg,
    float* __restrict__ outpred)
{
    const int cell = blockIdx.x;
    const int col  = cell >> 4;
    if (x[col] == 0) {
        if (threadIdx.x == 0) outpred[cell] = 0.0f;
        return;
    }

    __shared__ uint32_t snew[NUM_CELLS / 32];
    __shared__ uint32_t sprev[NUM_CELLS / 32];
    __shared__ int sfire;
    for (int i = threadIdx.x; i < NUM_CELLS / 32; i += 256) {
        snew[i]  = newbits[i];
        sprev[i] = prevbits[i];
    }
    if (threadIdx.x == 0) sfire = 0;
    __syncthreads();

    const int na  = (snew[cell >> 5] >> (cell & 31)) & 1;
    const int upd = (*learnflag && na) ? (int)bestseg[cell] : -1;
    const float d = mod[0] * 0.1f;

    const int wv   = threadIdx.x >> 6;
    const int ln   = threadIdx.x & 63;
    const int half = ln >> 5;
    const int l32  = ln & 31;
    const size_t base = (size_t)cell * (SEGS * SYNS);

    int fire = 0;
    #pragma unroll
    for (int k = 0; k < 4; ++k) {
        const int seg = wv * 8 + k * 2 + half;
        const size_t off = base + (size_t)seg * SYNS + l32 * 4;
        int i0, i1, i2, i3, cn0, cn1, cn2, cn3;
        if (PACKED) {
            ushort4 pk = *(const ushort4*)(packed + off);
            i0 = pk.x & 0x3FFF; cn0 = (pk.x >> 14) & 1;
            i1 = pk.y & 0x3FFF; cn1 = (pk.y >> 14) & 1;
            i2 = pk.z & 0x3FFF; cn2 = (pk.z >> 14) & 1;
            i3 = pk.w & 0x3FFF; cn3 = (pk.w >> 14) & 1;
            if (seg == upd) {
                float4 v = *(const float4*)(vol + off);
                float4 q = *(const float4*)(cons + off);
                int pp0 = (sprev[i0 >> 5] >> (i0 & 31)) & 1;
                int pp1 = (sprev[i1 >> 5] >> (i1 & 31)) & 1;
                int pp2 = (sprev[i2 >> 5] >> (i2 & 31)) & 1;
                int pp3 = (sprev[i3 >> 5] >> (i3 & 31)) & 1;
                cn0 = ((v.x + (pp0 ? d : -d)) > 0.5f) || (q.x > 0.5f);
                cn1 = ((v.y + (pp1 ? d : -d)) > 0.5f) || (q.y > 0.5f);
                cn2 = ((v.z + (pp2 ? d : -d)) > 0.5f) || (q.z > 0.5f);
                cn3 = ((v.w + (pp3 ? d : -d)) > 0.5f) || (q.w > 0.5f);
            }
        } else {
            int4   c = *(const int4*)(conn + off);
            float4 v = *(const float4*)(vol + off);
            float4 q = *(const float4*)(cons + off);
            i0 = min(max(c.x, 0), NUM_CELLS - 1);
            i1 = min(max(c.y, 0), NUM_CELLS - 1);
            i2 = min(max(c.z, 0), NUM_CELLS - 1);
            i3 = min(max(c.w, 0), NUM_CELLS - 1);
            float vx = v.x, vy = v.y, vz = v.z, vw = v.w;
            if (seg == upd) {
                int pp0 = (sprev[i0 >> 5] >> (i0 & 31)) & 1;
                int pp1 = (sprev[i1 >> 5] >> (i1 & 31)) & 1;
                int pp2 = (sprev[i2 >> 5] >> (i2 & 31)) & 1;
                int pp3 = (sprev[i3 >> 5] >> (i3 & 31)) & 1;
                vx += pp0 ? d : -d; vy += pp1 ? d : -d;
                vz += pp2 ? d : -d; vw += pp3 ? d : -d;
            }
            cn0 = (vx > 0.5f) || (q.x > 0.5f);
            cn1 = (vy > 0.5f) || (q.y > 0.5f);
            cn2 = (vz > 0.5f) || (q.z > 0.5f);
            cn3 = (vw > 0.5f) || (q.w > 0.5f);
        }
        int pn0 = (snew[i0 >> 5] >> (i0 & 31)) & 1;
        int pn1 = (snew[i1 >> 5] >> (i1 & 31)) & 1;
        int pn2 = (snew[i2 >> 5] >> (i2 & 31)) & 1;
        int pn3 = (snew[i3 >> 5] >> (i3 & 31)) & 1;
        int cnt = (cn0 & pn0) + (cn1 & pn1) + (cn2 & pn2) + (cn3 & pn3);
        int r = reduce_half32(cnt);
        if (l32 == 0 && r >= ACT_THR) fire = 1;
    }
    if (fire) atomicOr(&sfire, 1);
    __syncthreads();
    if (threadIdx.x == 0) outpred[cell] = sfire ? 1.0f : 0.0f;
}

// ---------------------------------------------------------------------------
extern "C" void kernel_launch(void* const* d_in, const int* in_sizes, int n_in,
                              void* d_out, int out_size, void* d_ws, size_t ws_size,
                              hipStream_t stream) {
    const int*   x    = (const int*)d_in[0];
    const float* mod  = (const float*)d_in[1];
    const void*  prev = d_in[2];                 // bool array (dtype auto-detected)
    const int*   conn = (const int*)d_in[3];
    const float* vol  = (const float*)d_in[4];
    const float* cons = (const float*)d_in[5];
    float* out = (float*)d_out;  // [0..N) new_active, [N..2N) new_predictive, [2N] acc

    char* ws = (char*)d_ws;
    uint32_t* prevbits  = (uint32_t*)(ws + 0);        // 2048 B
    uint32_t* newbits   = (uint32_t*)(ws + 2048);     // 2048 B
    int*      learnflag = (int*)(ws + 4096);          // 16 B
    unsigned char* pred1   = (unsigned char*)(ws + 4352);
    unsigned char* bestseg = (unsigned char*)(ws + 4352 + NUM_CELLS);
    unsigned short* packed = (unsigned short*)(ws + 40960);
    const size_t packed_bytes = (size_t)NUM_CELLS * SEGS * SYNS * 2;  // 128 MiB
    const bool use_packed = ws_size >= (size_t)40960 + packed_bytes;

    pack_prev_kernel<<<1, 512, 0, stream>>>(prev, prevbits);
    if (use_packed)
        phase1_kernel<true><<<NUM_CELLS, 256, 0, stream>>>(x, prevbits, conn, vol,
                                                           cons, packed, pred1, bestseg);
    else
        phase1_kernel<false><<<NUM_CELLS, 256, 0, stream>>>(x, prevbits, conn, vol,
                                                            cons, packed, pred1, bestseg);
    mid_kernel<<<1, 1024, 0, stream>>>(x, mod, prevbits, pred1, newbits,
                                       learnflag, out);
    if (use_packed)
        phase3_kernel<true><<<NUM_CELLS, 256, 0, stream>>>(x, mod, prevbits, newbits,
                                                           learnflag, packed, conn, vol,
                                                           cons, bestseg, out + NUM_CELLS);
    else
        phase3_kernel<false><<<NUM_CELLS, 256, 0, stream>>>(x, mod, prevbits, newbits,
                                                            learnflag, packed, conn, vol,
                                                            cons, bestseg, out + NUM_CELLS);
}

// Round 4
// 136.302 us; speedup vs baseline: 1.2294x; 1.0323x over previous
//
#include <hip/hip_runtime.h>
#include <stdint.h>

#define COLUMNS   1024
#define CELLS     16
#define NUM_CELLS (COLUMNS * CELLS)   // 16384
#define SEGS      32
#define SYNS      128
#define ACT_THR   10
#define NB        2048                // blocks for the big scans
#define WPB       4                   // waves per block (256 threads)

typedef int            i32x4 __attribute__((ext_vector_type(4)));
typedef float          f32x4 __attribute__((ext_vector_type(4)));
typedef unsigned short u16x4 __attribute__((ext_vector_type(4)));

template<typename T>
__device__ __forceinline__ T ntload(const T* p) { return __builtin_nontemporal_load(p); }

// Butterfly-reduce v across each 32-lane half of a 64-lane wave; every lane
// in a half ends with the half's sum.
__device__ __forceinline__ int reduce_half32(int v) {
    v += __shfl_xor(v, 1);
    v += __shfl_xor(v, 2);
    v += __shfl_xor(v, 4);
    v += __shfl_xor(v, 8);
    v += __shfl_xor(v, 16);
    return v;
}

// ---------------------------------------------------------------------------
// Plan kernel (1 block, 1024 thr): pack prev bits (dtype auto-detect),
// ordered compaction of active columns, learnflag.
// ---------------------------------------------------------------------------
__global__ __launch_bounds__(1024) void plan_kernel(
    const void* __restrict__ prev, const int* __restrict__ x,
    const float* __restrict__ mod, uint32_t* __restrict__ prevbits,
    int* __restrict__ acols, int* __restrict__ acount, int* __restrict__ learnflag)
{
    __shared__ int s_isu8, s_any;
    __shared__ int wcnt[16], woff[16];
    const int t = threadIdx.x;
    const int* pi = (const int*)prev;
    if (t == 0) { s_isu8 = 0; s_any = 0; }
    __syncthreads();
    // int32-bool: every word 0/1. uint8-bool (random 0/1 bytes): a word >1 whp.
    int bad = 0;
    for (int k = t; k < NUM_CELLS / 4; k += 1024)
        if ((unsigned)pi[k] > 1u) bad = 1;
    if (bad) atomicOr(&s_isu8, 1);
    __syncthreads();

    if (t < 512) {
        uint32_t m = 0;
        if (s_isu8) {
            const unsigned char* p = (const unsigned char*)prev + (size_t)t * 32;
            #pragma unroll
            for (int j = 0; j < 32; ++j) m |= (p[j] ? 1u : 0u) << j;
        } else {
            const int* p = pi + (size_t)t * 32;
            #pragma unroll
            for (int j = 0; j < 32; ++j) m |= (p[j] ? 1u : 0u) << j;
        }
        prevbits[t] = m;
        if (m) atomicOr(&s_any, 1);
    }

    // ordered active-column compaction (1024 threads = 16 waves)
    const int ca = (x[t] != 0) ? 1 : 0;
    unsigned long long b = __ballot(ca != 0);
    const int wid = t >> 6, ln = t & 63;
    if (ln == 0) wcnt[wid] = __popcll(b);
    __syncthreads();
    if (t == 0) {
        int s = 0;
        for (int i = 0; i < 16; ++i) { woff[i] = s; s += wcnt[i]; }
        *acount = s;
        *learnflag = ((mod[0] != 0.0f) && s_any) ? 1 : 0;
    }
    __syncthreads();
    if (ca) acols[woff[wid] + __popcll(b & ((1ULL << ln) - 1ULL))] = t;
}

// ---------------------------------------------------------------------------
// Phase 1+2 fused: persistent blocks; each WAVE owns whole cells (no
// syncthreads/shared in the cell loop). 16 iters x (2 segs x 32 lanes x int4).
// Writes pred1, bestseg (first-argmax), and (PACK) the uint16 sideband
// {clipped conn | connected<<14}.
// ---------------------------------------------------------------------------
template<bool PACK>
__global__ __launch_bounds__(256) void phase1_kernel(
    const uint32_t* __restrict__ prevbits, const int* __restrict__ acols,
    const int* __restrict__ acount,
    const int* __restrict__ conn, const float* __restrict__ vol,
    const float* __restrict__ cons, unsigned short* __restrict__ packed,
    unsigned char* __restrict__ pred1, unsigned char* __restrict__ bestseg)
{
    __shared__ uint32_t sbits[NUM_CELLS / 32];
    for (int i = threadIdx.x; i < NUM_CELLS / 32; i += 256) sbits[i] = prevbits[i];
    __syncthreads();

    const int nc   = *acount * CELLS;
    const int wv   = threadIdx.x >> 6;
    const int ln   = threadIdx.x & 63;
    const int half = ln >> 5;
    const int l32  = ln & 31;
    const int gw   = blockIdx.x * WPB + wv;   // global wave id

    for (int idx = gw; idx < nc; idx += NB * WPB) {
        const int cell = acols[idx >> 4] * CELLS + (idx & 15);
        const size_t base = (size_t)cell * (SEGS * SYNS);
        int bestkey = -1, fire = 0;
        #pragma unroll 4
        for (int k = 0; k < 16; ++k) {
            const int seg = k * 2 + half;
            const size_t off = base + (size_t)seg * SYNS + l32 * 4;
            i32x4 c = ntload((const i32x4*)(conn + off));
            f32x4 v = ntload((const f32x4*)(vol + off));
            f32x4 q = ntload((const f32x4*)(cons + off));
            int i0 = min(max(c.x, 0), NUM_CELLS - 1);
            int i1 = min(max(c.y, 0), NUM_CELLS - 1);
            int i2 = min(max(c.z, 0), NUM_CELLS - 1);
            int i3 = min(max(c.w, 0), NUM_CELLS - 1);
            int p0 = (sbits[i0 >> 5] >> (i0 & 31)) & 1;
            int p1 = (sbits[i1 >> 5] >> (i1 & 31)) & 1;
            int p2 = (sbits[i2 >> 5] >> (i2 & 31)) & 1;
            int p3 = (sbits[i3 >> 5] >> (i3 & 31)) & 1;
            int cn0 = ((v.x > 0.5f) || (q.x > 0.5f)) ? 1 : 0;
            int cn1 = ((v.y > 0.5f) || (q.y > 0.5f)) ? 1 : 0;
            int cn2 = ((v.z > 0.5f) || (q.z > 0.5f)) ? 1 : 0;
            int cn3 = ((v.w > 0.5f) || (q.w > 0.5f)) ? 1 : 0;
            if (PACK) {
                u16x4 pk;
                pk.x = (unsigned short)(i0 | (cn0 << 14));
                pk.y = (unsigned short)(i1 | (cn1 << 14));
                pk.z = (unsigned short)(i2 | (cn2 << 14));
                pk.w = (unsigned short)(i3 | (cn3 << 14));
                *(u16x4*)(packed + off) = pk;
            }
            int cnt = (cn0 & p0) + (cn1 & p1) + (cn2 & p2) + (cn3 & p3);
            int ovl = p0 + p1 + p2 + p3;
            int r = reduce_half32(cnt | (ovl << 8));      // cnt<=128, ovl<=128
            bestkey = max(bestkey, ((r >> 8) << 8) | (255 - seg));
            fire |= ((r & 0xFF) >= ACT_THR) ? 1 : 0;
        }
        bestkey = max(bestkey, __shfl_xor(bestkey, 32));
        fire   |= __shfl_xor(fire, 32);
        if (ln == 0) {
            pred1[cell]   = (unsigned char)(fire ? 1 : 0);
            bestseg[cell] = (unsigned char)(255 - (bestkey & 0xFF));  // first max
        }
    }
}

// ---------------------------------------------------------------------------
// Mid (1 block, 1024 thr = 1 col/thread): col_has_pred, new_active floats +
// packed bits, acc; zero-fills new_predictive (phase3 overwrites active cells).
// ---------------------------------------------------------------------------
__global__ __launch_bounds__(1024) void mid_kernel(
    const int* __restrict__ x, const unsigned char* __restrict__ pred1,
    uint32_t* __restrict__ newbits, float* __restrict__ out)
{
    __shared__ unsigned char s_hp[COLUMNS];
    __shared__ unsigned char s_act[COLUMNS];
    __shared__ int s_nact, s_npred;
    const int t = threadIdx.x;
    if (t == 0) { s_nact = 0; s_npred = 0; }
    __syncthreads();

    {
        const int col = t;
        int ca = (x[col] != 0) ? 1 : 0;
        int hp = 0;
        if (ca) {
            #pragma unroll
            for (int k = 0; k < CELLS; ++k) hp |= pred1[col * CELLS + k];
            hp = hp ? 1 : 0;
        }
        s_act[col] = (unsigned char)ca;
        s_hp[col]  = (unsigned char)hp;
        unsigned long long ba = __ballot(ca != 0);
        unsigned long long bp = __ballot((ca && hp) != 0);
        if ((t & 63) == 0) {
            atomicAdd(&s_nact, __popcll(ba));
            atomicAdd(&s_npred, __popcll(bp));
        }
    }
    __syncthreads();

    if (t < NUM_CELLS / 32) {
        uint32_t m = 0;
        #pragma unroll
        for (int j = 0; j < 32; ++j) {
            const int cell = t * 32 + j;
            const int col  = cell >> 4;
            int na = s_act[col] && (s_hp[col] ? (pred1[cell] != 0) : 1);
            m |= (uint32_t)(na ? 1u : 0u) << j;
        }
        newbits[t] = m;
    }
    for (int i = t; i < NUM_CELLS; i += 1024) {
        const int col = i >> 4;
        int na = s_act[col] && (s_hp[col] ? (pred1[i] != 0) : 1);
        out[i] = na ? 1.0f : 0.0f;
        out[NUM_CELLS + i] = 0.0f;   // default new_predictive (inactive cols)
    }
    __syncthreads();

    if (t == 0) {
        float acc = (s_nact > 0) ? (float)s_npred / (float)max(s_nact, 1) : 1.0f;
        out[2 * NUM_CELLS] = acc;
    }
}

// ---------------------------------------------------------------------------
// Phase 3: persistent wave-per-cell. PACKED path streams only the uint16
// sideband; the single updated segment of a winner cell re-reads its vol/cons
// row (clip(x,0,1)>0.5 == x>0.5, exact). Fallback re-reads everything.
// ---------------------------------------------------------------------------
template<bool PACKED>
__global__ __launch_bounds__(256) void phase3_kernel(
    const uint32_t* __restrict__ prevbits, const uint32_t* __restrict__ newbits,
    const int* __restrict__ acols, const int* __restrict__ acount,
    const int* __restrict__ learnflag, const float* __restrict__ mod,
    const unsigned short* __restrict__ packed, const int* __restrict__ conn,
    const float* __restrict__ vol, const float* __restrict__ cons,
    const unsigned char* __restrict__ bestseg, float* __restrict__ outpred)
{
    __shared__ uint32_t snew[NUM_CELLS / 32];
    __shared__ uint32_t sprev[NUM_CELLS / 32];
    for (int i = threadIdx.x; i < NUM_CELLS / 32; i += 256) {
        snew[i]  = newbits[i];
        sprev[i] = prevbits[i];
    }
    __syncthreads();

    const int nc   = *acount * CELLS;
    const int lf   = *learnflag;
    const float d  = mod[0] * 0.1f;
    const int wv   = threadIdx.x >> 6;
    const int ln   = threadIdx.x & 63;
    const int half = ln >> 5;
    const int l32  = ln & 31;
    const int gw   = blockIdx.x * WPB + wv;

    for (int idx = gw; idx < nc; idx += NB * WPB) {
        const int cell = acols[idx >> 4] * CELLS + (idx & 15);
        const size_t base = (size_t)cell * (SEGS * SYNS);
        const int na  = (snew[cell >> 5] >> (cell & 31)) & 1;
        const int upd = (lf && na) ? (int)bestseg[cell] : -1;
        int fire = 0;
        #pragma unroll 4
        for (int k = 0; k < 16; ++k) {
            const int seg = k * 2 + half;
            const size_t off = base + (size_t)seg * SYNS + l32 * 4;
            int i0, i1, i2, i3, cn0, cn1, cn2, cn3;
            if (PACKED) {
                u16x4 pk = *(const u16x4*)(packed + off);
                i0 = pk.x & 0x3FFF; cn0 = (pk.x >> 14) & 1;
                i1 = pk.y & 0x3FFF; cn1 = (pk.y >> 14) & 1;
                i2 = pk.z & 0x3FFF; cn2 = (pk.z >> 14) & 1;
                i3 = pk.w & 0x3FFF; cn3 = (pk.w >> 14) & 1;
                if (seg == upd) {
                    f32x4 v = *(const f32x4*)(vol + off);
                    f32x4 q = *(const f32x4*)(cons + off);
                    int pp0 = (sprev[i0 >> 5] >> (i0 & 31)) & 1;
                    int pp1 = (sprev[i1 >> 5] >> (i1 & 31)) & 1;
                    int pp2 = (sprev[i2 >> 5] >> (i2 & 31)) & 1;
                    int pp3 = (sprev[i3 >> 5] >> (i3 & 31)) & 1;
                    cn0 = ((v.x + (pp0 ? d : -d)) > 0.5f) || (q.x > 0.5f);
                    cn1 = ((v.y + (pp1 ? d : -d)) > 0.5f) || (q.y > 0.5f);
                    cn2 = ((v.z + (pp2 ? d : -d)) > 0.5f) || (q.z > 0.5f);
                    cn3 = ((v.w + (pp3 ? d : -d)) > 0.5f) || (q.w > 0.5f);
                }
            } else {
                i32x4 c = ntload((const i32x4*)(conn + off));
                f32x4 v = ntload((const f32x4*)(vol + off));
                f32x4 q = ntload((const f32x4*)(cons + off));
                i0 = min(max(c.x, 0), NUM_CELLS - 1);
                i1 = min(max(c.y, 0), NUM_CELLS - 1);
                i2 = min(max(c.z, 0), NUM_CELLS - 1);
                i3 = min(max(c.w, 0), NUM_CELLS - 1);
                float vx = v.x, vy = v.y, vz = v.z, vw = v.w;
                if (seg == upd) {
                    int pp0 = (sprev[i0 >> 5] >> (i0 & 31)) & 1;
                    int pp1 = (sprev[i1 >> 5] >> (i1 & 31)) & 1;
                    int pp2 = (sprev[i2 >> 5] >> (i2 & 31)) & 1;
                    int pp3 = (sprev[i3 >> 5] >> (i3 & 31)) & 1;
                    vx += pp0 ? d : -d; vy += pp1 ? d : -d;
                    vz += pp2 ? d : -d; vw += pp3 ? d : -d;
                }
                cn0 = (vx > 0.5f) || (q.x > 0.5f);
                cn1 = (vy > 0.5f) || (q.y > 0.5f);
                cn2 = (vz > 0.5f) || (q.z > 0.5f);
                cn3 = (vw > 0.5f) || (q.w > 0.5f);
            }
            int pn0 = (snew[i0 >> 5] >> (i0 & 31)) & 1;
            int pn1 = (snew[i1 >> 5] >> (i1 & 31)) & 1;
            int pn2 = (snew[i2 >> 5] >> (i2 & 31)) & 1;
            int pn3 = (snew[i3 >> 5] >> (i3 & 31)) & 1;
            int cnt = (cn0 & pn0) + (cn1 & pn1) + (cn2 & pn2) + (cn3 & pn3);
            fire |= (reduce_half32(cnt) >= ACT_THR) ? 1 : 0;
        }
        fire |= __shfl_xor(fire, 32);
        if (ln == 0) outpred[cell] = fire ? 1.0f : 0.0f;
    }
}

// ---------------------------------------------------------------------------
extern "C" void kernel_launch(void* const* d_in, const int* in_sizes, int n_in,
                              void* d_out, int out_size, void* d_ws, size_t ws_size,
                              hipStream_t stream) {
    const int*   x    = (const int*)d_in[0];
    const float* mod  = (const float*)d_in[1];
    const void*  prev = d_in[2];                 // bool array (dtype auto-detected)
    const int*   conn = (const int*)d_in[3];
    const float* vol  = (const float*)d_in[4];
    const float* cons = (const float*)d_in[5];
    float* out = (float*)d_out;  // [0..N) new_active, [N..2N) new_predictive, [2N] acc

    char* ws = (char*)d_ws;
    uint32_t* prevbits  = (uint32_t*)(ws + 0);         // 2048 B
    uint32_t* newbits   = (uint32_t*)(ws + 2048);      // 2048 B
    int*      learnflag = (int*)(ws + 4096);
    int*      acount    = (int*)(ws + 4160);
    int*      acols     = (int*)(ws + 4352);           // 4 KiB
    unsigned char* pred1   = (unsigned char*)(ws + 8704);   // 16 KiB
    unsigned char* bestseg = (unsigned char*)(ws + 25088);  // 16 KiB
    unsigned short* packed = (unsigned short*)(ws + 65536); // 128 MiB
    const size_t packed_bytes = (size_t)NUM_CELLS * SEGS * SYNS * 2;
    const bool use_packed = ws_size >= (size_t)65536 + packed_bytes;

    plan_kernel<<<1, 1024, 0, stream>>>(prev, x, mod, prevbits, acols, acount,
                                        learnflag);
    if (use_packed)
        phase1_kernel<true><<<NB, 256, 0, stream>>>(prevbits, acols, acount, conn,
                                                    vol, cons, packed, pred1, bestseg);
    else
        phase1_kernel<false><<<NB, 256, 0, stream>>>(prevbits, acols, acount, conn,
                                                     vol, cons, packed, pred1, bestseg);
    mid_kernel<<<1, 1024, 0, stream>>>(x, pred1, newbits, out);
    if (use_packed)
        phase3_kernel<true><<<NB, 256, 0, stream>>>(prevbits, newbits, acols, acount,
                                                    learnflag, mod, packed, conn, vol,
                                                    cons, bestseg, out + NUM_CELLS);
    else
        phase3_kernel<false><<<NB, 256, 0, stream>>>(prevbits, newbits, acols, acount,
                                                     learnflag, mod, packed, conn, vol,
                                                     cons, bestseg, out + NUM_CELLS);
}